// Round 13
// baseline (186.420 us; speedup 1.0000x reference)
//
#include <hip/hip_runtime.h>
#include <math.h>

#define NN 50000
#define NE 800000
#define D 64
#define NC 40
#define NBUCK 196   // ceil(NN/256) coarse buckets (bucket = dst >> 8)
#define SLAB 16384  // slots per bucket slab (avg fill ~4082; no overflow possible)
#define EPB 4096    // edges per scatter block
#define PADIDX 50000u          // ELL padding index -> dedicated zero row
#define PADPAT 0xC350C350u     // two u16 PADIDX

typedef unsigned short u16;
typedef unsigned int u32;

__device__ __forceinline__ u16 f32_to_bf16(float v) {
    u32 x = __float_as_uint(v);
    x += 0x7FFFu + ((x >> 16) & 1u);  // round-to-nearest-even
    return (u16)(x >> 16);
}
// packed u32 = two bf16: low u16 = dim 2k, high u16 = dim 2k+1
__device__ __forceinline__ float bflo(u32 v) { return __uint_as_float(v << 16); }
__device__ __forceinline__ float bfhi(u32 v) { return __uint_as_float(v & 0xffff0000u); }

// ---------------- phase 1: bin edges into coarse bucket slabs ----------------

__global__ __launch_bounds__(256) void bucket_scatter(const int* __restrict__ ei,
                                                      int* __restrict__ cursor,
                                                      u32* __restrict__ slab) {
    __shared__ int sums[256];
    __shared__ int lofs[256];
    __shared__ int lcur[256];
    __shared__ int gbase[256];
    __shared__ int tot_s;
    __shared__ u32 sorted[EPB];
    __shared__ int gdest[EPB];
    int tid = threadIdx.x;

    u32 pk[16];
    int nmine = 0;
    int e0 = blockIdx.x * EPB + tid * 16;
    if (e0 < NE) {
        nmine = 16;
#pragma unroll
        for (int j = 0; j < 4; ++j) {
            int4 ss = *(const int4*)&ei[e0 + j * 4];
            int4 dd = *(const int4*)&ei[NE + e0 + j * 4];
            pk[j * 4 + 0] = ((u32)dd.x << 16) | (u32)ss.x;
            pk[j * 4 + 1] = ((u32)dd.y << 16) | (u32)ss.y;
            pk[j * 4 + 2] = ((u32)dd.z << 16) | (u32)ss.z;
            pk[j * 4 + 3] = ((u32)dd.w << 16) | (u32)ss.w;
        }
    }

    sums[tid] = 0;
    __syncthreads();
    for (int j = 0; j < nmine; ++j) atomicAdd(&sums[pk[j] >> 24], 1);
    __syncthreads();
    int v = sums[tid];
    __syncthreads();
    for (int off = 1; off < 256; off <<= 1) {
        int u = (tid >= off) ? sums[tid - off] : 0;
        __syncthreads();
        sums[tid] += u;
        __syncthreads();
    }
    lofs[tid] = sums[tid] - v;
    lcur[tid] = sums[tid] - v;
    if (tid == 255) tot_s = sums[255];
    if (tid < NBUCK) gbase[tid] = atomicAdd(&cursor[tid], v);
    __syncthreads();

    for (int j = 0; j < nmine; ++j) {
        u32 p = pk[j];
        int bin = (int)(p >> 24);
        int pos = atomicAdd(&lcur[bin], 1);
        sorted[pos] = p;
        gdest[pos] = bin * SLAB + gbase[bin] + (pos - lofs[bin]);
    }
    __syncthreads();

    int tot = tot_s;
    for (int i = tid; i < tot; i += 256) slab[gdest[i]] = sorted[i];
}

// ---------------- phase 2: per-bucket ELL tile in LDS, coalesced write-out ----------------

// Padding slots hold PADIDX -> loads from the zero row (no VALU masking in gather).
__global__ __launch_bounds__(256) void ell_build(const u32* __restrict__ slab,
                                                 const int* __restrict__ cursor,
                                                 u16* __restrict__ ell,
                                                 int* __restrict__ cnt,
                                                 float* __restrict__ dinv) {
    __shared__ u16 ell_lds[256 * 64];  // 32 KB
    __shared__ int cnt_lds[256];
    int b = blockIdx.x, tid = threadIdx.x;
    uint4* z = (uint4*)ell_lds;
    for (int i = tid; i < 2048; i += 256) z[i] = make_uint4(PADPAT, PADPAT, PADPAT, PADPAT);
    cnt_lds[tid] = 0;
    __syncthreads();

    int nE = cursor[b];
    const u32* run = slab + b * SLAB;
    int base = b * 256;
    for (int i = tid; i < nE; i += 256) {
        u32 p = run[i];
        int dl = (int)(p >> 16) - base;
        int r = atomicAdd(&cnt_lds[dl], 1);
        if (r < 64) ell_lds[dl * 64 + r] = (u16)(p & 0xffffu);
    }
    __syncthreads();

    int nNodes = NN - base; if (nNodes > 256) nNodes = 256;
    const uint4* s4 = (const uint4*)ell_lds;
    uint4* d4 = (uint4*)(ell + (size_t)base * 64);
    int n4 = nNodes * 8;
    for (int i = tid; i < n4; i += 256) d4[i] = s4[i];
    if (tid < nNodes) {
        int c = cnt_lds[tid];
        cnt[base + tid] = c;
        dinv[base + tid] = rsqrtf((float)c + 1.0f);
    }
}

// ---------------- layer-0 dense transform ----------------

// C[row,:] = bf16( (A[row,:] @ W) * dinv[row] ). Block 0 also zeroes the pad
// row (index NN) of BOTH message buffers (d_ws is re-poisoned every launch).
__global__ __launch_bounds__(256) void gemm64_bf16(const float* __restrict__ A,
                                                   const float* __restrict__ W,
                                                   const float* __restrict__ dinv,
                                                   u16* __restrict__ C,
                                                   u16* __restrict__ other) {
    __shared__ float Ws[64 * 64];
    __shared__ float As[4 * 64];
    int tid = threadIdx.x;
    if (blockIdx.x == 0 && tid >= 240) {  // zero pad rows: 2 x 8 uint4 = 2 x 128 B
        int t = tid - 240;
        u16* dst = (t < 8) ? C : other;
        ((uint4*)(dst + (size_t)NN * 64))[t & 7] = make_uint4(0, 0, 0, 0);
    }
    for (int i = tid; i < 64 * 64; i += 256) Ws[i] = W[i];
    int r = tid >> 6, c = tid & 63;
    int row = blockIdx.x * 4 + r;
    if (row < NN) As[r * 64 + c] = A[row * 64 + c];
    __syncthreads();
    if (row < NN) {
        float acc = 0.0f;
#pragma unroll
        for (int k = 0; k < 64; ++k) acc += As[r * 64 + k] * Ws[k * 64 + c];
        C[row * 64 + c] = f32_to_bf16(acc * dinv[row]);
    }
}

// ---------------- gather core: quarter-wave, 4 nodes/wave, 16-deep, maskless ----------------

// Lane l = q*16+p: quarter q owns node base+q; lane p holds dims [4p..4p+3] (uint2).
// Index row in ONE uint2/lane; per-edge broadcast via __shfl with compile-time
// selects. Padding indices point at the zero row -> unconditional accumulate.
__device__ __forceinline__ void gather_quad(const u16* __restrict__ ell,
                                            const int* __restrict__ cnt,
                                            const uint2* __restrict__ hs2,
                                            int base, int l,
                                            float& a0, float& a1, float& a2, float& a3) {
    int q = l >> 4, p = l & 15;
    int node = base + q;
    int4 c4 = *(const int4*)&cnt[base];
    int d0 = c4.x > 64 ? 64 : c4.x;
    int d1 = c4.y > 64 ? 64 : c4.y;
    int d2 = c4.z > 64 ? 64 : c4.z;
    int d3 = c4.w > 64 ? 64 : c4.w;
    int m01 = (d0 > d1) ? d0 : d1;
    int m23 = (d2 > d3) ? d2 : d3;
    int degmax = (m01 > m23) ? m01 : m23;  // wave-uniform

    uint2 iv = ((const uint2*)(ell + (size_t)node * 64))[p];  // slots 4p..4p+3

    uint2 sv = hs2[node * 16 + p];  // self-loop row
    a0 = bflo(sv.x); a1 = bfhi(sv.x); a2 = bflo(sv.y); a3 = bfhi(sv.y);
    float e0 = 0.0f, e1 = 0.0f, e2 = 0.0f, e3 = 0.0f;

    for (int m = 0; m < degmax; m += 16) {
        uint2 st[16];
#pragma unroll
        for (int u = 0; u < 16; ++u) {
            u32 wsel = ((u >> 1) & 1) ? iv.y : iv.x;            // compile-time select
            int bc = __shfl((int)wsel, (l & 48) + (m >> 2) + (u >> 2));
            int sid = (u & 1) ? (int)((u32)bc >> 16) : (int)(bc & 0xffff);
            st[u] = hs2[sid * 16 + p];                          // 16 independent loads
        }
#pragma unroll
        for (int u = 0; u < 16; ++u) {
            u32 x = st[u].x, y = st[u].y;                       // pad rows read zeros
            if (u & 1) { e0 += bflo(x); e1 += bfhi(x); e2 += bflo(y); e3 += bfhi(y); }
            else       { a0 += bflo(x); a1 += bfhi(x); a2 += bflo(y); a3 += bfhi(y); }
        }
    }
    a0 += e0; a1 += e1; a2 += e2; a3 += e3;
}

// ---------------- fused gather kernels ----------------

// Layer 1: gather+tanh (4 nodes/wave) -> per-wave LDS stage -> h1 @ W2 * dinv -> bf16.
__global__ __launch_bounds__(256, 6) void gather_l1_fused(const u16* __restrict__ ell,
                                                          const int* __restrict__ cnt,
                                                          const u16* __restrict__ hs,
                                                          const float* __restrict__ dinv,
                                                          const float* __restrict__ b1,
                                                          const float* __restrict__ W2,
                                                          u16* __restrict__ hs_out) {
    __shared__ float Ws[64 * 64];
    __shared__ __align__(16) float hb[4][4][64];
    int tid = threadIdx.x;
    for (int i = tid; i < 64 * 64; i += 256) Ws[i] = W2[i];
    __syncthreads();  // weight staging only

    int r = tid >> 6, l = tid & 63, q = l >> 4, p = l & 15;
    int base = (blockIdx.x * 4 + r) * 4;  // NN divisible by 16
    int node = base + q;

    float a0, a1, a2, a3;
    gather_quad(ell, cnt, (const uint2*)hs, base, l, a0, a1, a2, a3);

    float dv = dinv[node];
    float4 bb = *(const float4*)&b1[p * 4];
    float4 h = make_float4(tanhf(a0 * dv + bb.x), tanhf(a1 * dv + bb.y),
                           tanhf(a2 * dv + bb.z), tanhf(a3 * dv + bb.w));
    *(float4*)&hb[r][q][p * 4] = h;
    __builtin_amdgcn_wave_barrier();  // same-wave DS ordering only

    int d = l;
    float4 dvv = *(const float4*)&dinv[base];
    float o0 = 0.0f, o1 = 0.0f, o2 = 0.0f, o3 = 0.0f;
#pragma unroll
    for (int k4 = 0; k4 < 16; ++k4) {
        float4 h0 = *(const float4*)&hb[r][0][k4 * 4];
        float4 h1 = *(const float4*)&hb[r][1][k4 * 4];
        float4 h2 = *(const float4*)&hb[r][2][k4 * 4];
        float4 h3 = *(const float4*)&hb[r][3][k4 * 4];
        float w0 = Ws[(k4 * 4 + 0) * 64 + d];
        float w1 = Ws[(k4 * 4 + 1) * 64 + d];
        float w2 = Ws[(k4 * 4 + 2) * 64 + d];
        float w3 = Ws[(k4 * 4 + 3) * 64 + d];
        o0 += h0.x * w0 + h0.y * w1 + h0.z * w2 + h0.w * w3;
        o1 += h1.x * w0 + h1.y * w1 + h1.z * w2 + h1.w * w3;
        o2 += h2.x * w0 + h2.y * w1 + h2.z * w2 + h2.w * w3;
        o3 += h3.x * w0 + h3.y * w1 + h3.z * w2 + h3.w * w3;
    }
    hs_out[(base + 0) * 64 + d] = f32_to_bf16(o0 * dvv.x);
    hs_out[(base + 1) * 64 + d] = f32_to_bf16(o1 * dvv.y);
    hs_out[(base + 2) * 64 + d] = f32_to_bf16(o2 * dvv.z);
    hs_out[(base + 3) * 64 + d] = f32_to_bf16(o3 * dvv.w);
}

// Layer 2: gather+tanh -> h_out (f32, float4 coalesced) -> classifier epilogue.
__global__ __launch_bounds__(256, 6) void gather_l2_fused(const u16* __restrict__ ell,
                                                          const int* __restrict__ cnt,
                                                          const u16* __restrict__ hs,
                                                          const float* __restrict__ dinv,
                                                          const float* __restrict__ b2,
                                                          const float* __restrict__ Wc,
                                                          const float* __restrict__ bc,
                                                          float* __restrict__ h_out,
                                                          float* __restrict__ out) {
    __shared__ float Ws[64 * NC];
    __shared__ float bs[NC];
    __shared__ __align__(16) float hb[4][4][64];
    int tid = threadIdx.x;
    for (int i = tid; i < 64 * NC; i += 256) Ws[i] = Wc[i];
    if (tid < NC) bs[tid] = bc[tid];
    __syncthreads();

    int r = tid >> 6, l = tid & 63, q = l >> 4, p = l & 15;
    int base = (blockIdx.x * 4 + r) * 4;
    int node = base + q;

    float a0, a1, a2, a3;
    gather_quad(ell, cnt, (const uint2*)hs, base, l, a0, a1, a2, a3);

    float dv = dinv[node];
    float4 bb = *(const float4*)&b2[p * 4];
    float4 h = make_float4(tanhf(a0 * dv + bb.x), tanhf(a1 * dv + bb.y),
                           tanhf(a2 * dv + bb.z), tanhf(a3 * dv + bb.w));
    *(float4*)&h_out[node * 64 + p * 4] = h;  // 16 lanes x 16B = full row, coalesced
    *(float4*)&hb[r][q][p * 4] = h;
    __builtin_amdgcn_wave_barrier();

    int d = l;
    int dc = (d < NC) ? d : NC - 1;
    float bcd = bs[dc];
    float o0 = bcd, o1 = bcd, o2 = bcd, o3 = bcd;
#pragma unroll
    for (int k4 = 0; k4 < 16; ++k4) {
        float4 v0 = *(const float4*)&hb[r][0][k4 * 4];
        float4 v1 = *(const float4*)&hb[r][1][k4 * 4];
        float4 v2 = *(const float4*)&hb[r][2][k4 * 4];
        float4 v3 = *(const float4*)&hb[r][3][k4 * 4];
        float w0 = Ws[(k4 * 4 + 0) * NC + dc];
        float w1 = Ws[(k4 * 4 + 1) * NC + dc];
        float w2 = Ws[(k4 * 4 + 2) * NC + dc];
        float w3 = Ws[(k4 * 4 + 3) * NC + dc];
        o0 += v0.x * w0 + v0.y * w1 + v0.z * w2 + v0.w * w3;
        o1 += v1.x * w0 + v1.y * w1 + v1.z * w2 + v1.w * w3;
        o2 += v2.x * w0 + v2.y * w1 + v2.z * w2 + v2.w * w3;
        o3 += v3.x * w0 + v3.y * w1 + v3.z * w2 + v3.w * w3;
    }
    if (d < NC) {
        out[(base + 0) * NC + d] = o0;
        out[(base + 1) * NC + d] = o1;
        out[(base + 2) * NC + d] = o2;
        out[(base + 3) * NC + d] = o3;
    }
}

// ---------------- launch ----------------

extern "C" void kernel_launch(void* const* d_in, const int* in_sizes, int n_in,
                              void* d_out, int out_size, void* d_ws, size_t ws_size,
                              hipStream_t stream) {
    const float* x  = (const float*)d_in[0];
    const int*   ei = (const int*)d_in[1];
    const float* W1 = (const float*)d_in[2];
    const float* b1 = (const float*)d_in[3];
    const float* W2 = (const float*)d_in[4];
    const float* b2 = (const float*)d_in[5];
    const float* Wc = (const float*)d_in[6];
    const float* bc = (const float*)d_in[7];

    float* out   = (float*)d_out;   // [NN, 40]
    float* h_out = out + NN * NC;   // [NN, 64]

    // workspace (16B-aligned segments); hs buffers have NN+1 rows (pad zero row)
    u32*   slab   = (u32*)d_ws;                       // NBUCK*SLAB u32 = 12.8 MB
    int*   cursor = (int*)(slab + NBUCK * SLAB);      // NBUCK (+pad to 256)
    int*   cnt    = cursor + 256;                     // NN i32
    float* dinv   = (float*)(cnt + NN);               // NN f32
    u16*   ell    = (u16*)(dinv + NN);                // NN*64 u16 = 6.4 MB
    u16*   hsA    = ell + (size_t)NN * 64;            // (NN+1)*64 u16
    u16*   hsB    = hsA + (size_t)(NN + 1) * 64;      // (NN+1)*64 u16

    const int scatBlocks   = (NE + EPB - 1) / EPB;    // 196
    const int nodeBlocks4  = (NN + 3) / 4;            // 12500
    const int nodeBlocks16 = NN / 16;                 // 3125

    // two-phase binned ELL build
    hipMemsetAsync(cursor, 0, NBUCK * sizeof(int), stream);
    bucket_scatter<<<scatBlocks, 256, 0, stream>>>(ei, cursor, slab);
    ell_build<<<NBUCK, 256, 0, stream>>>(slab, cursor, ell, cnt, dinv);

    // layer 0 transform (also zeroes both pad rows), then fused layers 1 and 2
    gemm64_bf16<<<nodeBlocks4, 256, 0, stream>>>(x, W1, dinv, hsA, hsB);
    gather_l1_fused<<<nodeBlocks16, 256, 0, stream>>>(ell, cnt, hsA, dinv, b1, W2, hsB);
    gather_l2_fused<<<nodeBlocks16, 256, 0, stream>>>(ell, cnt, hsB, dinv, b2, Wc, bc,
                                                      h_out, out);
}

// Round 14
// 182.437 us; speedup vs baseline: 1.0218x; 1.0218x over previous
//
#include <hip/hip_runtime.h>
#include <math.h>

#define NN 50000
#define NE 800000
#define D 64
#define NC 40
#define NBUCK 196   // ceil(NN/256) coarse buckets (bucket = dst >> 8)
#define SLAB 16384  // slots per bucket slab (avg fill ~4082; no overflow possible)
#define EPB 4096    // edges per scatter block
#define PADIDX 50000u          // ELL padding index -> dedicated zero row
#define PADPAT 0xC350C350u     // two u16 PADIDX

typedef unsigned short u16;
typedef unsigned int u32;

__device__ __forceinline__ u16 f32_to_bf16(float v) {
    u32 x = __float_as_uint(v);
    x += 0x7FFFu + ((x >> 16) & 1u);  // round-to-nearest-even
    return (u16)(x >> 16);
}
// packed u32 = two bf16: low u16 = dim 2k, high u16 = dim 2k+1
__device__ __forceinline__ float bflo(u32 v) { return __uint_as_float(v << 16); }
__device__ __forceinline__ float bfhi(u32 v) { return __uint_as_float(v & 0xffff0000u); }

// ---------------- phase 1: bin edges into coarse bucket slabs ----------------

__global__ __launch_bounds__(256) void bucket_scatter(const int* __restrict__ ei,
                                                      int* __restrict__ cursor,
                                                      u32* __restrict__ slab) {
    __shared__ int sums[256];
    __shared__ int lofs[256];
    __shared__ int lcur[256];
    __shared__ int gbase[256];
    __shared__ int tot_s;
    __shared__ u32 sorted[EPB];
    __shared__ int gdest[EPB];
    int tid = threadIdx.x;

    u32 pk[16];
    int nmine = 0;
    int e0 = blockIdx.x * EPB + tid * 16;
    if (e0 < NE) {
        nmine = 16;
#pragma unroll
        for (int j = 0; j < 4; ++j) {
            int4 ss = *(const int4*)&ei[e0 + j * 4];
            int4 dd = *(const int4*)&ei[NE + e0 + j * 4];
            pk[j * 4 + 0] = ((u32)dd.x << 16) | (u32)ss.x;
            pk[j * 4 + 1] = ((u32)dd.y << 16) | (u32)ss.y;
            pk[j * 4 + 2] = ((u32)dd.z << 16) | (u32)ss.z;
            pk[j * 4 + 3] = ((u32)dd.w << 16) | (u32)ss.w;
        }
    }

    sums[tid] = 0;
    __syncthreads();
    for (int j = 0; j < nmine; ++j) atomicAdd(&sums[pk[j] >> 24], 1);
    __syncthreads();
    int v = sums[tid];
    __syncthreads();
    for (int off = 1; off < 256; off <<= 1) {
        int u = (tid >= off) ? sums[tid - off] : 0;
        __syncthreads();
        sums[tid] += u;
        __syncthreads();
    }
    lofs[tid] = sums[tid] - v;
    lcur[tid] = sums[tid] - v;
    if (tid == 255) tot_s = sums[255];
    if (tid < NBUCK) gbase[tid] = atomicAdd(&cursor[tid], v);
    __syncthreads();

    for (int j = 0; j < nmine; ++j) {
        u32 p = pk[j];
        int bin = (int)(p >> 24);
        int pos = atomicAdd(&lcur[bin], 1);
        sorted[pos] = p;
        gdest[pos] = bin * SLAB + gbase[bin] + (pos - lofs[bin]);
    }
    __syncthreads();

    int tot = tot_s;
    for (int i = tid; i < tot; i += 256) slab[gdest[i]] = sorted[i];
}

// ---------------- phase 2: per-bucket ELL tile in LDS, coalesced write-out ----------------

// Padding slots hold PADIDX -> loads from the zero row (no VALU masking in gather).
__global__ __launch_bounds__(256) void ell_build(const u32* __restrict__ slab,
                                                 const int* __restrict__ cursor,
                                                 u16* __restrict__ ell,
                                                 int* __restrict__ cnt,
                                                 float* __restrict__ dinv) {
    __shared__ u16 ell_lds[256 * 64];  // 32 KB
    __shared__ int cnt_lds[256];
    int b = blockIdx.x, tid = threadIdx.x;
    uint4* z = (uint4*)ell_lds;
    for (int i = tid; i < 2048; i += 256) z[i] = make_uint4(PADPAT, PADPAT, PADPAT, PADPAT);
    cnt_lds[tid] = 0;
    __syncthreads();

    int nE = cursor[b];
    const u32* run = slab + b * SLAB;
    int base = b * 256;
    for (int i = tid; i < nE; i += 256) {
        u32 p = run[i];
        int dl = (int)(p >> 16) - base;
        int r = atomicAdd(&cnt_lds[dl], 1);
        if (r < 64) ell_lds[dl * 64 + r] = (u16)(p & 0xffffu);
    }
    __syncthreads();

    int nNodes = NN - base; if (nNodes > 256) nNodes = 256;
    const uint4* s4 = (const uint4*)ell_lds;
    uint4* d4 = (uint4*)(ell + (size_t)base * 64);
    int n4 = nNodes * 8;
    for (int i = tid; i < n4; i += 256) d4[i] = s4[i];
    if (tid < nNodes) {
        int c = cnt_lds[tid];
        cnt[base + tid] = c;
        dinv[base + tid] = rsqrtf((float)c + 1.0f);
    }
}

// ---------------- layer-0 dense transform ----------------

// C[row,:] = bf16( (A[row,:] @ W) * dinv[row] ). Block 0 also zeroes the pad
// row (index NN) of BOTH message buffers (d_ws is re-poisoned every launch).
__global__ __launch_bounds__(256) void gemm64_bf16(const float* __restrict__ A,
                                                   const float* __restrict__ W,
                                                   const float* __restrict__ dinv,
                                                   u16* __restrict__ C,
                                                   u16* __restrict__ other) {
    __shared__ float Ws[64 * 64];
    __shared__ float As[4 * 64];
    int tid = threadIdx.x;
    if (blockIdx.x == 0 && tid >= 240) {  // zero pad rows: 2 x 8 uint4 = 2 x 128 B
        int t = tid - 240;
        u16* dst = (t < 8) ? C : other;
        ((uint4*)(dst + (size_t)NN * 64))[t & 7] = make_uint4(0, 0, 0, 0);
    }
    for (int i = tid; i < 64 * 64; i += 256) Ws[i] = W[i];
    int r = tid >> 6, c = tid & 63;
    int row = blockIdx.x * 4 + r;
    if (row < NN) As[r * 64 + c] = A[row * 64 + c];
    __syncthreads();
    if (row < NN) {
        float acc = 0.0f;
#pragma unroll
        for (int k = 0; k < 64; ++k) acc += As[r * 64 + k] * Ws[k * 64 + c];
        C[row * 64 + c] = f32_to_bf16(acc * dinv[row]);
    }
}

// ---------------- gather core: quarter-wave, 4 nodes/wave, 16-deep, maskless ----------------

// Lane l = q*16+p: quarter q owns node base+q; lane p holds dims [4p..4p+3] (uint2).
// Index row in ONE uint2/lane; per-edge broadcast via __shfl with compile-time
// selects. Padding indices point at the zero row -> unconditional accumulate.
__device__ __forceinline__ void gather_quad(const u16* __restrict__ ell,
                                            const int* __restrict__ cnt,
                                            const uint2* __restrict__ hs2,
                                            int base, int l,
                                            float& a0, float& a1, float& a2, float& a3) {
    int q = l >> 4, p = l & 15;
    int node = base + q;
    int4 c4 = *(const int4*)&cnt[base];
    int d0 = c4.x > 64 ? 64 : c4.x;
    int d1 = c4.y > 64 ? 64 : c4.y;
    int d2 = c4.z > 64 ? 64 : c4.z;
    int d3 = c4.w > 64 ? 64 : c4.w;
    int m01 = (d0 > d1) ? d0 : d1;
    int m23 = (d2 > d3) ? d2 : d3;
    int degmax = (m01 > m23) ? m01 : m23;  // wave-uniform

    uint2 iv = ((const uint2*)(ell + (size_t)node * 64))[p];  // slots 4p..4p+3

    uint2 sv = hs2[node * 16 + p];  // self-loop row
    a0 = bflo(sv.x); a1 = bfhi(sv.x); a2 = bflo(sv.y); a3 = bfhi(sv.y);
    float e0 = 0.0f, e1 = 0.0f, e2 = 0.0f, e3 = 0.0f;

    for (int m = 0; m < degmax; m += 16) {
        uint2 st[16];
#pragma unroll
        for (int u = 0; u < 16; ++u) {
            u32 wsel = ((u >> 1) & 1) ? iv.y : iv.x;            // compile-time select
            int bc = __shfl((int)wsel, (l & 48) + (m >> 2) + (u >> 2));
            int sid = (u & 1) ? (int)((u32)bc >> 16) : (int)(bc & 0xffff);
            st[u] = hs2[sid * 16 + p];                          // 16 independent loads
        }
#pragma unroll
        for (int u = 0; u < 16; ++u) {
            u32 x = st[u].x, y = st[u].y;                       // pad rows read zeros
            if (u & 1) { e0 += bflo(x); e1 += bfhi(x); e2 += bflo(y); e3 += bfhi(y); }
            else       { a0 += bflo(x); a1 += bfhi(x); a2 += bflo(y); a3 += bfhi(y); }
        }
    }
    a0 += e0; a1 += e1; a2 += e2; a3 += e3;
}

// ---------------- fused gather kernels ----------------

// Layer 1: gather+tanh (4 nodes/wave) -> per-wave LDS stage -> h1 @ W2 * dinv -> bf16.
// No occupancy hint: the 16-deep batch needs its VGPRs (r13 lesson: capping VGPR
// splits the batch and re-exposes latency).
__global__ __launch_bounds__(256) void gather_l1_fused(const u16* __restrict__ ell,
                                                       const int* __restrict__ cnt,
                                                       const u16* __restrict__ hs,
                                                       const float* __restrict__ dinv,
                                                       const float* __restrict__ b1,
                                                       const float* __restrict__ W2,
                                                       u16* __restrict__ hs_out) {
    __shared__ float Ws[64 * 64];
    __shared__ __align__(16) float hb[4][4][64];
    int tid = threadIdx.x;
    for (int i = tid; i < 64 * 64; i += 256) Ws[i] = W2[i];
    __syncthreads();  // weight staging only

    int r = tid >> 6, l = tid & 63, q = l >> 4, p = l & 15;
    int base = (blockIdx.x * 4 + r) * 4;  // NN divisible by 16
    int node = base + q;

    float a0, a1, a2, a3;
    gather_quad(ell, cnt, (const uint2*)hs, base, l, a0, a1, a2, a3);

    float dv = dinv[node];
    float4 bb = *(const float4*)&b1[p * 4];
    float4 h = make_float4(tanhf(a0 * dv + bb.x), tanhf(a1 * dv + bb.y),
                           tanhf(a2 * dv + bb.z), tanhf(a3 * dv + bb.w));
    *(float4*)&hb[r][q][p * 4] = h;
    __builtin_amdgcn_wave_barrier();  // same-wave DS ordering only

    int d = l;
    float4 dvv = *(const float4*)&dinv[base];
    float o0 = 0.0f, o1 = 0.0f, o2 = 0.0f, o3 = 0.0f;
#pragma unroll
    for (int k4 = 0; k4 < 16; ++k4) {
        float4 h0 = *(const float4*)&hb[r][0][k4 * 4];
        float4 h1 = *(const float4*)&hb[r][1][k4 * 4];
        float4 h2 = *(const float4*)&hb[r][2][k4 * 4];
        float4 h3 = *(const float4*)&hb[r][3][k4 * 4];
        float w0 = Ws[(k4 * 4 + 0) * 64 + d];
        float w1 = Ws[(k4 * 4 + 1) * 64 + d];
        float w2 = Ws[(k4 * 4 + 2) * 64 + d];
        float w3 = Ws[(k4 * 4 + 3) * 64 + d];
        o0 += h0.x * w0 + h0.y * w1 + h0.z * w2 + h0.w * w3;
        o1 += h1.x * w0 + h1.y * w1 + h1.z * w2 + h1.w * w3;
        o2 += h2.x * w0 + h2.y * w1 + h2.z * w2 + h2.w * w3;
        o3 += h3.x * w0 + h3.y * w1 + h3.z * w2 + h3.w * w3;
    }
    hs_out[(base + 0) * 64 + d] = f32_to_bf16(o0 * dvv.x);
    hs_out[(base + 1) * 64 + d] = f32_to_bf16(o1 * dvv.y);
    hs_out[(base + 2) * 64 + d] = f32_to_bf16(o2 * dvv.z);
    hs_out[(base + 3) * 64 + d] = f32_to_bf16(o3 * dvv.w);
}

// Layer 2: gather+tanh -> h_out (f32, float4 coalesced) -> classifier epilogue.
__global__ __launch_bounds__(256) void gather_l2_fused(const u16* __restrict__ ell,
                                                       const int* __restrict__ cnt,
                                                       const u16* __restrict__ hs,
                                                       const float* __restrict__ dinv,
                                                       const float* __restrict__ b2,
                                                       const float* __restrict__ Wc,
                                                       const float* __restrict__ bc,
                                                       float* __restrict__ h_out,
                                                       float* __restrict__ out) {
    __shared__ float Ws[64 * NC];
    __shared__ float bs[NC];
    __shared__ __align__(16) float hb[4][4][64];
    int tid = threadIdx.x;
    for (int i = tid; i < 64 * NC; i += 256) Ws[i] = Wc[i];
    if (tid < NC) bs[tid] = bc[tid];
    __syncthreads();

    int r = tid >> 6, l = tid & 63, q = l >> 4, p = l & 15;
    int base = (blockIdx.x * 4 + r) * 4;
    int node = base + q;

    float a0, a1, a2, a3;
    gather_quad(ell, cnt, (const uint2*)hs, base, l, a0, a1, a2, a3);

    float dv = dinv[node];
    float4 bb = *(const float4*)&b2[p * 4];
    float4 h = make_float4(tanhf(a0 * dv + bb.x), tanhf(a1 * dv + bb.y),
                           tanhf(a2 * dv + bb.z), tanhf(a3 * dv + bb.w));
    *(float4*)&h_out[node * 64 + p * 4] = h;  // 16 lanes x 16B = full row, coalesced
    *(float4*)&hb[r][q][p * 4] = h;
    __builtin_amdgcn_wave_barrier();

    int d = l;
    int dc = (d < NC) ? d : NC - 1;
    float bcd = bs[dc];
    float o0 = bcd, o1 = bcd, o2 = bcd, o3 = bcd;
#pragma unroll
    for (int k4 = 0; k4 < 16; ++k4) {
        float4 v0 = *(const float4*)&hb[r][0][k4 * 4];
        float4 v1 = *(const float4*)&hb[r][1][k4 * 4];
        float4 v2 = *(const float4*)&hb[r][2][k4 * 4];
        float4 v3 = *(const float4*)&hb[r][3][k4 * 4];
        float w0 = Ws[(k4 * 4 + 0) * NC + dc];
        float w1 = Ws[(k4 * 4 + 1) * NC + dc];
        float w2 = Ws[(k4 * 4 + 2) * NC + dc];
        float w3 = Ws[(k4 * 4 + 3) * NC + dc];
        o0 += v0.x * w0 + v0.y * w1 + v0.z * w2 + v0.w * w3;
        o1 += v1.x * w0 + v1.y * w1 + v1.z * w2 + v1.w * w3;
        o2 += v2.x * w0 + v2.y * w1 + v2.z * w2 + v2.w * w3;
        o3 += v3.x * w0 + v3.y * w1 + v3.z * w2 + v3.w * w3;
    }
    if (d < NC) {
        out[(base + 0) * NC + d] = o0;
        out[(base + 1) * NC + d] = o1;
        out[(base + 2) * NC + d] = o2;
        out[(base + 3) * NC + d] = o3;
    }
}

// ---------------- launch ----------------

extern "C" void kernel_launch(void* const* d_in, const int* in_sizes, int n_in,
                              void* d_out, int out_size, void* d_ws, size_t ws_size,
                              hipStream_t stream) {
    const float* x  = (const float*)d_in[0];
    const int*   ei = (const int*)d_in[1];
    const float* W1 = (const float*)d_in[2];
    const float* b1 = (const float*)d_in[3];
    const float* W2 = (const float*)d_in[4];
    const float* b2 = (const float*)d_in[5];
    const float* Wc = (const float*)d_in[6];
    const float* bc = (const float*)d_in[7];

    float* out   = (float*)d_out;   // [NN, 40]
    float* h_out = out + NN * NC;   // [NN, 64]

    // workspace (16B-aligned segments); hs buffers have NN+1 rows (pad zero row)
    u32*   slab   = (u32*)d_ws;                       // NBUCK*SLAB u32 = 12.8 MB
    int*   cursor = (int*)(slab + NBUCK * SLAB);      // NBUCK (+pad to 256)
    int*   cnt    = cursor + 256;                     // NN i32
    float* dinv   = (float*)(cnt + NN);               // NN f32
    u16*   ell    = (u16*)(dinv + NN);                // NN*64 u16 = 6.4 MB
    u16*   hsA    = ell + (size_t)NN * 64;            // (NN+1)*64 u16
    u16*   hsB    = hsA + (size_t)(NN + 1) * 64;      // (NN+1)*64 u16

    const int scatBlocks   = (NE + EPB - 1) / EPB;    // 196
    const int nodeBlocks4  = (NN + 3) / 4;            // 12500
    const int nodeBlocks16 = NN / 16;                 // 3125

    // two-phase binned ELL build
    hipMemsetAsync(cursor, 0, NBUCK * sizeof(int), stream);
    bucket_scatter<<<scatBlocks, 256, 0, stream>>>(ei, cursor, slab);
    ell_build<<<NBUCK, 256, 0, stream>>>(slab, cursor, ell, cnt, dinv);

    // layer 0 transform (also zeroes both pad rows), then fused layers 1 and 2
    gemm64_bf16<<<nodeBlocks4, 256, 0, stream>>>(x, W1, dinv, hsA, hsB);
    gather_l1_fused<<<nodeBlocks16, 256, 0, stream>>>(ell, cnt, hsA, dinv, b1, W2, hsB);
    gather_l2_fused<<<nodeBlocks16, 256, 0, stream>>>(ell, cnt, hsB, dinv, b2, Wc, bc,
                                                      h_out, out);
}